// Round 12
// baseline (2952.701 us; speedup 1.0000x reference)
//
#include <hip/hip_runtime.h>
#include <hip/hip_bf16.h>
#include <math.h>

// ---------------------------------------------------------------------------
// ViT forward (B=32, N=197, D=768, FF=3072, 12 layers) — round 12:
// Base = round 11 (best, 2888 us). One change: BN=64 variant of the SAME
// mm_nt datapath (parameter change, not sync change) for the TLP-starved
// GEMMs. Grids: QKV 450->1800, FF2 300->1200, PV 384->768, scores 128->256,
// patch 294->588 WGs. FF1 stays BN=128 (already 4.7 blocks/CU).
// Wave layout BN=64: 4 waves x (32 rows x 64 cols), acc[2][4]; LDS 24 KiB.
// ---------------------------------------------------------------------------

namespace {
constexpr int DIM    = 768;
constexpr int FF_DIM = 3072;
constexpr int QKVN   = 2304;               // 3*DIM fused QKV output width
constexpr int NTOK   = 197;
constexpr int NBATCH = 32;
constexpr int NLAYER = 12;
constexpr int ROWS   = NBATCH * NTOK;      // 6304
constexpr int NPATCH = 196;
constexpr int PROWS  = NBATCH * NPATCH;    // 6272
constexpr int KVPAD  = 256;                // padded K for P@V GEMM
constexpr float LN_EPS = 1e-5f;
}

typedef __attribute__((ext_vector_type(8))) __bf16 bf16x8;
typedef __attribute__((ext_vector_type(4))) float  f32x4;

// ---------------- threefry2x32 gumbel (JAX jax.random.key(1)) ---------------
__device__ __forceinline__ unsigned rotl32(unsigned v, int d) {
  return (v << d) | (v >> (32 - d));
}

__device__ __forceinline__ float gumbel_noise(unsigned idx) {
  const unsigned ks0 = 0u, ks1 = 1u, ks2 = 0x1BD11BDBu;
  unsigned x0 = 0u + ks0;
  unsigned x1 = idx + ks1;
#define TFR(r) { x0 += x1; x1 = rotl32(x1, (r)); x1 ^= x0; }
  TFR(13) TFR(15) TFR(26) TFR(6)   x0 += ks1; x1 += ks2 + 1u;
  TFR(17) TFR(29) TFR(16) TFR(24)  x0 += ks2; x1 += ks0 + 2u;
  TFR(13) TFR(15) TFR(26) TFR(6)   x0 += ks0; x1 += ks1 + 3u;
  TFR(17) TFR(29) TFR(16) TFR(24)  x0 += ks1; x1 += ks2 + 4u;
  TFR(13) TFR(15) TFR(26) TFR(6)   x0 += ks2; x1 += ks0 + 5u;
#undef TFR
  unsigned bits = x0 ^ x1;
  float f = __uint_as_float((bits >> 9) | 0x3f800000u) - 1.0f;
  const float tiny = 1.17549435e-38f;
  float u = fmaxf(tiny, f + tiny);
  return -logf(-logf(u));
}

// ---------------- wave-level block reductions (256-thread blocks) -----------
__device__ __forceinline__ float block_sum(float v, float* red4) {
  const int lane = threadIdx.x & 63, wid = threadIdx.x >> 6;
  #pragma unroll
  for (int o = 32; o > 0; o >>= 1) v += __shfl_xor(v, o);
  if (lane == 0) red4[wid] = v;
  __syncthreads();
  const float r = red4[0] + red4[1] + red4[2] + red4[3];
  __syncthreads();
  return r;
}

__device__ __forceinline__ float block_max(float v, float* red4) {
  const int lane = threadIdx.x & 63, wid = threadIdx.x >> 6;
  #pragma unroll
  for (int o = 32; o > 0; o >>= 1) v = fmaxf(v, __shfl_xor(v, o));
  if (lane == 0) red4[wid] = v;
  __syncthreads();
  const float r = fmaxf(fmaxf(red4[0], red4[1]), fmaxf(red4[2], red4[3]));
  __syncthreads();
  return r;
}

// ---------------- async 16B global -> LDS ----------------------------------
__device__ __forceinline__ void async_copy16(const void* g, void* l) {
  __builtin_amdgcn_global_load_lds(
      (const __attribute__((address_space(1))) unsigned*)g,
      (__attribute__((address_space(3))) unsigned*)l, 16, 0, 0);
}

// ---------------- XCD-bijective swizzle (m204) ------------------------------
__device__ __forceinline__ int xcd_swizzle(int id, int nwg) {
  const int q = nwg >> 3, r = nwg & 7;
  const int xcd = id & 7, pos = id >> 3;
  return (xcd < r ? xcd * (q + 1) : r * (q + 1) + (xcd - r) * q) + pos;
}

// ---------------- 128xBN single-buffer MFMA GEMM (NT) + T2 swizzle ----------
// A: [M][K] bf16 (lda, batch stride sA); B: [N][K] bf16 (ldb, sB)
// C: f32 (STORE=0) or bf16 (STORE=1). Grid: x = tilesM*tilesN, y = batch
// (y also reusable as split-K index via sA/sB = k-offset, sC = buffer offset).
// BK=64 fixed. LDS rows of 64 bf16 (128 B); data at (row, slot16B) is global
// (row, slot ^ (row&7)) via pre-swizzled global source (rule #21); ds_read
// applies the same XOR. Measured 0 bank conflicts (round 5+).
// BN=128: 4 waves as 2x2 of 64x64, acc[4][4], LDS 32 KiB.
// BN=64 : 4 waves as 4x1 of 32x64, acc[2][4], LDS 24 KiB (TLP variant for
//         small grids: doubles the workgroup count of narrow-N GEMMs).
template<int STORE, bool GELU, int BN>
__global__ void mm_nt(
    const __hip_bfloat16* __restrict__ A, long sA, int lda,
    const __hip_bfloat16* __restrict__ B, long sB, int ldb,
    void* __restrict__ Cv, long sC, int ldc,
    int M, int N, int K, const float* __restrict__ bias) {
  constexpr int NWN   = (BN == 128) ? 2 : 1;   // waves along N
  constexpr int WROWS = (BN == 128) ? 64 : 32; // rows per wave
  constexpr int MI    = WROWS / 16;            // A frags (4 or 2)
  constexpr int NJ    = 4;                     // B frags (64 cols / 16)
  constexpr int NPB   = BN / 32;               // B staging passes (4 or 2)
  __shared__ __hip_bfloat16 As[128 * 64];
  __shared__ __hip_bfloat16 Bs[BN * 64];
  const int bz = blockIdx.y;
  A += (long)bz * sA;
  B += (long)bz * sB;
  const int tilesN = (N + BN - 1) / BN;
  const int id = xcd_swizzle(blockIdx.x, gridDim.x);
  const int row0 = (id / tilesN) * 128, col0 = (id % tilesN) * BN;

  const int tid = threadIdx.x, lane = tid & 63, wid = tid >> 6;
  const int wr = (wid / NWN) * WROWS, wc = (wid % NWN) * 64;
  const int fr = lane & 15;
  const int kh = lane >> 4;
  const int fsw = fr & 7;                 // read-side XOR key
  f32x4 acc[MI][NJ] = {};

  const int elem = wid * 512 + lane * 8;  // linear elem within a 2048-elem pass

  for (int k0 = 0; k0 < K; k0 += 64) {
    #pragma unroll
    for (int c = 0; c < 4; c++) {         // A: 128 rows, 4 passes
      const int e = c * 2048 + elem;
      const int r = e >> 6;               // LDS row this lane's 16B lands in
      const int slot = (e >> 3) & 7;      // 16B slot within the row
      const int ksw = ((slot ^ (r & 7)) << 3);  // pre-swizzled source k
      async_copy16(A + (long)(row0 + r) * lda + k0 + ksw,
                   (char*)As + c * 4096 + wid * 1024);
    }
    #pragma unroll
    for (int c = 0; c < NPB; c++) {       // B: BN rows, BN/32 passes
      const int e = c * 2048 + elem;
      const int r = e >> 6;
      const int slot = (e >> 3) & 7;
      const int ksw = ((slot ^ (r & 7)) << 3);
      async_copy16(B + (long)(col0 + r) * ldb + k0 + ksw,
                   (char*)Bs + c * 4096 + wid * 1024);
    }
    __syncthreads();
    #pragma unroll
    for (int ks = 0; ks < 2; ks++) {
      bf16x8 a[MI], b[NJ];
      const int sl = (((ks << 2) | kh) ^ fsw) << 4;   // swizzled slot byte-off
      #pragma unroll
      for (int i = 0; i < MI; i++) {
        const int row = wr + i * 16 + fr;
        a[i] = *(const bf16x8*)((const char*)As + row * 128 + sl);
      }
      #pragma unroll
      for (int j = 0; j < NJ; j++) {
        const int row = wc + j * 16 + fr;
        b[j] = *(const bf16x8*)((const char*)Bs + row * 128 + sl);
      }
      #pragma unroll
      for (int i = 0; i < MI; i++)
        #pragma unroll
        for (int j = 0; j < NJ; j++)
          acc[i][j] = __builtin_amdgcn_mfma_f32_16x16x32_bf16(
              a[i], b[j], acc[i][j], 0, 0, 0);
    }
    __syncthreads();
  }

  // epilogue: D layout col = lane&15, row = (lane>>4)*4 + reg
  #pragma unroll
  for (int i = 0; i < MI; i++) {
    #pragma unroll
    for (int j = 0; j < NJ; j++) {
      #pragma unroll
      for (int t = 0; t < 4; t++) {
        const int r  = row0 + wr + i * 16 + kh * 4 + t;
        const int cc = col0 + wc + j * 16 + fr;
        if (r < M && cc < N) {
          float v = acc[i][j][t];
          if (bias) v += bias[cc];
          if (GELU) v = 0.5f * v * (1.0f + erff(v * 0.70710678118654752f));
          if (STORE == 0)
            ((float*)Cv)[(long)bz * sC + (long)r * ldc + cc] = v;
          else
            ((__hip_bfloat16*)Cv)[(long)bz * sC + (long)r * ldc + cc] =
                __float2bfloat16(v);
        }
      }
    }
  }
}

// ---------------- f32 [K][N] -> bf16 [N][K] transpose (single matrix) -------
__global__ void transpose_bf16_kernel(const float* __restrict__ W,
                                      __hip_bfloat16* __restrict__ Wt,
                                      int K, int N) {
  __shared__ float t[32][33];
  const int k0 = blockIdx.x * 32, n0 = blockIdx.y * 32;
  const int tx = threadIdx.x & 31, ty = threadIdx.x >> 5;
  #pragma unroll
  for (int i = 0; i < 32; i += 8)
    t[ty + i][tx] = W[(long)(k0 + ty + i) * N + n0 + tx];
  __syncthreads();
  #pragma unroll
  for (int i = 0; i < 32; i += 8)
    Wt[(long)(n0 + ty + i) * K + k0 + tx] = __float2bfloat16(t[tx][ty + i]);
}

// ---------------- weight transpose, 64x64 tiles, y = layer ------------------
// Round-8 version (0 bank conflicts, HBM-bound at ~2.5 TB/s).
__global__ void wtrans_kernel(const float* __restrict__ Wq,
                              const float* __restrict__ Wk,
                              const float* __restrict__ Wv,
                              const float* __restrict__ W1,
                              const float* __restrict__ W2,
                              __hip_bfloat16* __restrict__ wqkv_t,
                              __hip_bfloat16* __restrict__ w1_t,
                              __hip_bfloat16* __restrict__ w2_t,
                              long sq, long s1, long s2) {
  __shared__ float t[64][65];
  const int l = blockIdx.y;
  Wq += (long)l * DIM * DIM;  Wk += (long)l * DIM * DIM;
  Wv += (long)l * DIM * DIM;
  W1 += (long)l * DIM * FF_DIM;  W2 += (long)l * FF_DIM * DIM;
  wqkv_t += (long)l * sq;  w1_t += (long)l * s1;  w2_t += (long)l * s2;

  const int id = blockIdx.x;
  const float* W; __hip_bfloat16* O; int K, N, k0, n0;
  if (id < 432) {                       // Wq/Wk/Wv: 3 x 12x12 tiles of 64
    const int m = id / 144, tt = id % 144;
    W = (m == 0) ? Wq : (m == 1) ? Wk : Wv;
    O = wqkv_t + (long)m * DIM * DIM;
    K = DIM; N = DIM; k0 = (tt / 12) * 64; n0 = (tt % 12) * 64;
  } else if (id < 1008) {               // W1 [768][3072]: 12x48 tiles
    const int tt = id - 432;
    W = W1; O = w1_t;
    K = DIM; N = FF_DIM; k0 = (tt / 48) * 64; n0 = (tt % 48) * 64;
  } else {                              // W2 [3072][768]: 48x12 tiles
    const int tt = id - 1008;
    W = W2; O = w2_t;
    K = FF_DIM; N = DIM; k0 = (tt / 12) * 64; n0 = (tt % 12) * 64;
  }
  const int tx = threadIdx.x & 63, ty = threadIdx.x >> 6;  // 64 x 4
  #pragma unroll
  for (int i = 0; i < 16; i++) {
    const int r = ty + i * 4;
    t[r][tx] = W[(long)(k0 + r) * N + n0 + tx];
  }
  __syncthreads();
  #pragma unroll
  for (int i = 0; i < 16; i++) {
    const int r = ty + i * 4;                    // output row (n)
    O[(long)(n0 + r) * K + k0 + tx] = __float2bfloat16(t[tx][r]);
  }
}

// ---------------- fused QKV bias, all layers, built once --------------------
__global__ void build_qkv_bias(const float* __restrict__ bq,
                               const float* __restrict__ bk,
                               const float* __restrict__ bv,
                               float* __restrict__ o) {
  const int l = blockIdx.x;
  for (int d = threadIdx.x; d < DIM; d += 256) {
    o[l * QKVN + d]           = bq[l * DIM + d];
    o[l * QKVN + DIM + d]     = bk[l * DIM + d];
    o[l * QKVN + 2 * DIM + d] = bv[l * DIM + d];
  }
}

// ---------------- V slice -> vt[b][d][tok] (tok padded to 256 w/ zeros) -----
__global__ void vtrans_kernel(const __hip_bfloat16* __restrict__ qkv,
                              __hip_bfloat16* __restrict__ vt) {
  __shared__ __hip_bfloat16 s[64][68];
  const int b = blockIdx.z;
  const int t0 = blockIdx.x * 64;
  const int d0 = blockIdx.y * 64;
  const int tx = threadIdx.x & 63, ty = threadIdx.x >> 6;  // 64 x 4
  for (int i = ty; i < 64; i += 4) {
    const int t = t0 + i;
    __hip_bfloat16 v = __float2bfloat16(0.f);
    if (t < NTOK) v = qkv[(long)(b * NTOK + t) * QKVN + 2 * DIM + d0 + tx];
    s[i][tx] = v;
  }
  __syncthreads();
  for (int i = ty; i < 64; i += 4)
    vt[((long)b * DIM + d0 + i) * KVPAD + t0 + tx] = s[tx][i];
}

// ---------------- patch embedding helpers -----------------------------------
__global__ void im2col_kernel(const float* __restrict__ x,
                              __hip_bfloat16* __restrict__ col) {
  const int p = blockIdx.x;
  const int b = p / NPATCH, pi = p % NPATCH;
  const int h = pi / 14, w = pi % 14;
  for (int e = threadIdx.x; e < DIM; e += 256) {
    const int c = e >> 8, r = e & 255, pp = r >> 4, q = r & 15;
    col[(long)p * DIM + e] = __float2bfloat16(
        x[(((long)b * 3 + c) * 224 + h * 16 + pp) * 224 + w * 16 + q]);
  }
}

__global__ void assemble_kernel(const float* __restrict__ tmp,
                                const float* __restrict__ cls,
                                const float* __restrict__ pos,
                                float* __restrict__ tok,
                                __hip_bfloat16* __restrict__ tok_bf) {
  const int row = blockIdx.x;
  const int b = row / NTOK, n = row % NTOK;
  for (int d = threadIdx.x; d < DIM; d += 256) {
    float v = (n == 0) ? cls[d] : tmp[(long)(b * NPATCH + n - 1) * DIM + d];
    v += pos[n * DIM + d];
    tok[(long)row * DIM + d] = v;
    tok_bf[(long)row * DIM + d] = __float2bfloat16(v);
  }
}

// ---------------- fused gumbel + softmax (per q-row block) ------------------
__global__ void softmax_kernel(const float* __restrict__ sc,
                               __hip_bfloat16* __restrict__ P, int layer) {
  __shared__ float red[4];
  const int row = blockIdx.x;
  const int b = row / NTOK, n = row % NTOK;
  const int tid = threadIdx.x;
  const long base = (long)row * NTOK;
  const float inv_sqrt_d = 0.036084391824351615f;

  float x = -INFINITY;
  if (tid < NTOK) {
    const unsigned idx =
        ((((unsigned)layer * NBATCH + b) * NTOK + n) * NTOK) + tid;
    x = sc[base + tid] * inv_sqrt_d + gumbel_noise(idx);
  }
  const float mx = block_max(x, red);
  float ex = (tid < NTOK) ? expf(x - mx) : 0.f;
  const float s = block_sum(ex, red);
  const float pv = (tid < NTOK) ? ex / s : 0.f;
  P[(long)row * KVPAD + tid] = __float2bfloat16(pv);
}

// ---------------- residual add (1-2 partials + opt bias) + LayerNorm --------
__global__ void add_ln_kernel(float* __restrict__ tok,
                              __hip_bfloat16* __restrict__ tok_bf,
                              const float* __restrict__ res,
                              const float* __restrict__ res2,
                              const float* __restrict__ rbias,
                              const float* __restrict__ g,
                              const float* __restrict__ beta) {
  __shared__ float red[4];
  const int row = blockIdx.x;
  const int tid = threadIdx.x;
  const long base = (long)row * DIM;
  float v[3];
  float s = 0.f;
  #pragma unroll
  for (int i = 0; i < 3; i++) {
    const int d = tid + (i << 8);
    float r = tok[base + d] + res[base + d];
    if (res2)  r += res2[base + d];
    if (rbias) r += rbias[d];
    v[i] = r;
    s += r;
  }
  const float mean = block_sum(s, red) * (1.0f / DIM);
  float s2 = 0.f;
  #pragma unroll
  for (int i = 0; i < 3; i++) { const float dd = v[i] - mean; s2 += dd * dd; }
  const float var = block_sum(s2, red) * (1.0f / DIM);
  const float inv = 1.0f / sqrtf(var + LN_EPS);
  #pragma unroll
  for (int i = 0; i < 3; i++) {
    const int d = tid + (i << 8);
    const float o = (v[i] - mean) * inv * g[d] + beta[d];
    tok[base + d] = o;
    tok_bf[base + d] = __float2bfloat16(o);
  }
}

// ---------------- final LN (cls row) + head ---------------------------------
__global__ void head_kernel(const float* __restrict__ tok,
                            const float* __restrict__ g,
                            const float* __restrict__ beta,
                            const float* __restrict__ hw,
                            const float* __restrict__ hb,
                            float* __restrict__ out) {
  __shared__ float red[4];
  __shared__ float xn[DIM];
  const int b = blockIdx.x;
  const int tid = threadIdx.x;
  const float* xr = tok + (long)b * NTOK * DIM;
  float v[3];
  float s = 0.f;
  #pragma unroll
  for (int i = 0; i < 3; i++) { v[i] = xr[tid + (i << 8)]; s += v[i]; }
  const float mean = block_sum(s, red) * (1.0f / DIM);
  float s2 = 0.f;
  #pragma unroll
  for (int i = 0; i < 3; i++) { const float dd = v[i] - mean; s2 += dd * dd; }
  const float var = block_sum(s2, red) * (1.0f / DIM);
  const float inv = 1.0f / sqrtf(var + LN_EPS);
  #pragma unroll
  for (int i = 0; i < 3; i++) {
    const int d = tid + (i << 8);
    xn[d] = (v[i] - mean) * inv * g[d] + beta[d];
  }
  __syncthreads();
  for (int c = tid; c < 100; c += 256) {
    float acc = hb[c];
    for (int d = 0; d < DIM; d++) acc += xn[d] * hw[d * 100 + c];
    out[b * 100 + c] = acc;
  }
}

// ---------------------------------------------------------------------------
extern "C" void kernel_launch(void* const* d_in, const int* in_sizes, int n_in,
                              void* d_out, int out_size, void* d_ws, size_t ws_size,
                              hipStream_t stream) {
  const float* x        = (const float*)d_in[0];
  const float* patch_w  = (const float*)d_in[1];
  const float* patch_b  = (const float*)d_in[2];
  const float* cls_tok  = (const float*)d_in[3];
  const float* pos_emb  = (const float*)d_in[4];
  const float* Wq       = (const float*)d_in[5];
  const float* bq       = (const float*)d_in[6];
  const float* Wk       = (const float*)d_in[7];
  const float* bk       = (const float*)d_in[8];
  const float* Wv       = (const float*)d_in[9];
  const float* bv       = (const float*)d_in[10];
  const float* W1       = (const float*)d_in[11];
  const float* b1       = (const float*)d_in[12];
  const float* W2       = (const float*)d_in[13];
  const float* b2       = (const float*)d_in[14];
  const float* ln1_g    = (const float*)d_in[15];
  const float* ln1_b    = (const float*)d_in[16];
  const float* ln2_g    = (const float*)d_in[17];
  const float* ln2_b    = (const float*)d_in[18];
  const float* lnf_g    = (const float*)d_in[19];
  const float* lnf_b    = (const float*)d_in[20];
  const float* head_w   = (const float*)d_in[21];
  const float* head_b   = (const float*)d_in[22];
  float* out = (float*)d_out;

  // per-layer transposed-weight sizes (bf16 elems)
  const long WQKV = (long)QKVN * DIM;
  const long W1SZ = (long)FF_DIM * DIM;
  const long W2SZ = (long)DIM * FF_DIM;
  const long WLAYER = WQKV + W1SZ + W2SZ;

  const long F32N = 3L * 6400 * DIM + (long)NLAYER * QKVN;
  const long BF16FIX = 6400L * DIM + 6400L * FF_DIM +
                       (long)NBATCH * DIM * KVPAD + 6400L * KVPAD +
                       (long)DIM * DIM;
  const size_t need12 = (size_t)F32N * 4 + (size_t)(BF16FIX + 12 * WLAYER) * 2;
  const bool hoist = ws_size >= need12;
  const int NW = hoist ? NLAYER : 1;

  // ---- workspace layout ----
  float* fb = (float*)d_ws;
  long fo = 0;
  float* tok      = fb + fo; fo += 6400L * DIM;
  float* b4       = fb + fo; fo += 6400L * DIM;
  float* b4b      = fb + fo; fo += 6400L * DIM;      // FF2 split-K partial 1
  float* bias_all = fb + fo; fo += (long)NLAYER * QKVN;
  __hip_bfloat16* hbuf = (__hip_bfloat16*)(fb + fo);
  long ho = 0;
  __hip_bfloat16* tok_bf = hbuf + ho; ho += 6400L * DIM;
  __hip_bfloat16* qkv    = hbuf + ho;                // alias with ffout head
  __hip_bfloat16* ffout  = hbuf + ho; ho += 6400L * FF_DIM;
  // scores f32 aliases the ffout TAIL (beyond qkv's 6400*2304 bf16 elems)
  float* scbuf = (float*)(qkv + 6400L * QKVN);
  __hip_bfloat16* vt     = hbuf + ho; ho += (long)NBATCH * DIM * KVPAD;
  __hip_bfloat16* Pb     = hbuf + ho; ho += 6400L * KVPAD;
  __hip_bfloat16* pw_t   = hbuf + ho; ho += (long)DIM * DIM;
  __hip_bfloat16* wqkv_t = hbuf + ho; ho += (long)NW * WQKV;
  __hip_bfloat16* w1_t   = hbuf + ho; ho += (long)NW * W1SZ;
  __hip_bfloat16* w2_t   = hbuf + ho; ho += (long)NW * W2SZ;

  const long DD = (long)DIM * DIM;
  const long QKVSTRIDE = (long)NTOK * QKVN;
  const long TOKSTRIDE = (long)NTOK * DIM;
  const long SCSTRIDE  = (long)NTOK * NTOK;
  const long VTSTRIDE  = (long)DIM * KVPAD;
  const long PSTRIDE   = (long)NTOK * KVPAD;

  build_qkv_bias<<<NLAYER, 256, 0, stream>>>(bq, bk, bv, bias_all);

  // hoisted all-layer weight transpose (one dispatch) if ws permits
  if (hoist) {
    wtrans_kernel<<<dim3(1584, NLAYER), 256, 0, stream>>>(
        Wq, Wk, Wv, W1, W2, wqkv_t, w1_t, w2_t, WQKV, W1SZ, W2SZ);
  }

  // ---- patch embedding ----
  im2col_kernel<<<PROWS, 256, 0, stream>>>(x, ffout);
  transpose_bf16_kernel<<<dim3(DIM / 32, DIM / 32), 256, 0, stream>>>(
      patch_w, pw_t, DIM, DIM);
  mm_nt<0, false, 64><<<dim3(49 * 12, 1), 256, 0, stream>>>(
      ffout, 0, DIM, pw_t, 0, DIM, b4, 0, DIM, PROWS, DIM, DIM, patch_b);
  assemble_kernel<<<ROWS, 256, 0, stream>>>(b4, cls_tok, pos_emb, tok, tok_bf);

  for (int l = 0; l < NLAYER; l++) {
    __hip_bfloat16* wqkv_l = wqkv_t + (hoist ? (long)l * WQKV : 0);
    __hip_bfloat16* w1_l   = w1_t   + (hoist ? (long)l * W1SZ : 0);
    __hip_bfloat16* w2_l   = w2_t   + (hoist ? (long)l * W2SZ : 0);
    if (!hoist) {
      wtrans_kernel<<<dim3(1584, 1), 256, 0, stream>>>(
          Wq + l * DD, Wk + l * DD, Wv + l * DD,
          W1 + (long)l * DIM * FF_DIM, W2 + (long)l * FF_DIM * DIM,
          wqkv_l, w1_l, w2_l, 0, 0, 0);
    }

    // fused QKV (BN=64 -> 1800 WGs): [6304][2304] = tok_bf @ wqkv^T + bias
    mm_nt<1, false, 64><<<dim3(50 * (QKVN / 64), 1), 256, 0, stream>>>(
        tok_bf, 0, DIM, wqkv_l, 0, DIM, qkv, 0, QKVN,
        ROWS, QKVN, DIM, bias_all + l * QKVN);

    // V slice -> vt[b][d][tok] (zero-padded tok 197..255)
    vtrans_kernel<<<dim3(KVPAD / 64, DIM / 64, NBATCH), 256, 0, stream>>>(qkv, vt);

    // scores = Q @ K^T (f32 -> scbuf), Q/K lda=2304 slices (BN=64, 256 WGs)
    mm_nt<0, false, 64><<<dim3(2 * 4, NBATCH), 256, 0, stream>>>(
        qkv, QKVSTRIDE, QKVN, qkv + DIM, QKVSTRIDE, QKVN, scbuf, SCSTRIDE, NTOK,
        NTOK, NTOK, DIM, nullptr);

    // gumbel + softmax (6304 blocks -> full TLP for the VALU-heavy phase)
    softmax_kernel<<<ROWS, 256, 0, stream>>>(scbuf, Pb, l);

    // attn = P @ V (BN=64 -> 768 WGs; B = vt, K = KVPAD zero-padded)
    mm_nt<0, false, 64><<<dim3(2 * (DIM / 64), NBATCH), 256, 0, stream>>>(
        Pb, PSTRIDE, KVPAD, vt, VTSTRIDE, KVPAD, b4, TOKSTRIDE, DIM,
        NTOK, DIM, KVPAD, nullptr);

    add_ln_kernel<<<ROWS, 256, 0, stream>>>(tok, tok_bf, b4, nullptr, nullptr,
        ln1_g + l * DIM, ln1_b + l * DIM);

    // FF1 (BN=128, 1200 WGs — already TLP-rich; +bias+GELU, bf16 out);
    // ffout overwrites qkv + scbuf (both dead after attn)
    mm_nt<1, true, 128><<<dim3(50 * (FF_DIM / 128), 1), 256, 0, stream>>>(
        tok_bf, 0, DIM, w1_l, 0, DIM, ffout, 0, FF_DIM,
        ROWS, FF_DIM, DIM, b1 + l * FF_DIM);

    // FF2 split-K=2 (BN=64 -> 1200 WGs) via batch-stride trick: y = k-half.
    mm_nt<0, false, 64><<<dim3(50 * (DIM / 64), 2), 256, 0, stream>>>(
        ffout, 1536, FF_DIM, w2_l, 1536, FF_DIM,
        b4, 6400L * DIM, DIM, ROWS, DIM, 1536, nullptr);

    // LN2 folds partial sum + b2 bias
    add_ln_kernel<<<ROWS, 256, 0, stream>>>(tok, tok_bf, b4, b4b, b2 + l * DIM,
        ln2_g + l * DIM, ln2_b + l * DIM);
  }

  head_kernel<<<NBATCH, 256, 0, stream>>>(tok, lnf_g, lnf_b, head_w, head_b, out);
}

// Round 13
// 2886.211 us; speedup vs baseline: 1.0230x; 1.0230x over previous
//
#include <hip/hip_runtime.h>
#include <hip/hip_bf16.h>
#include <math.h>

// ---------------------------------------------------------------------------
// ViT forward (B=32, N=197, D=768, FF=3072, 12 layers) — round 13:
// EXACT revert to round-11 (session best, 2888 us). BN=64 reverted (R12:
// +64 us — halving BN doubles A-staging traffic per output element; TLP
// gain < intensity loss). Final configuration:
// - single-buffer 128^2 BK=64 mm_nt, T2 both-sides XOR swizzle (0 bank
//   conflicts), XCD-bijective tile swizzle
// - fused QKV GEMM + prebuilt bias; vtrans V; scores GEMM -> f32 scbuf
//   (aliased into ffout tail); 6304-block gumbel+softmax; PV GEMM
// - FF1 BN=128; FF2 split-K=2 folded into LN2
// - all-12-layer weight transpose hoisted to one dispatch
// - wave shfl_xor reductions in softmax/add_ln/head
// ---------------------------------------------------------------------------

namespace {
constexpr int DIM    = 768;
constexpr int FF_DIM = 3072;
constexpr int QKVN   = 2304;               // 3*DIM fused QKV output width
constexpr int NTOK   = 197;
constexpr int NBATCH = 32;
constexpr int NLAYER = 12;
constexpr int ROWS   = NBATCH * NTOK;      // 6304
constexpr int NPATCH = 196;
constexpr int PROWS  = NBATCH * NPATCH;    // 6272
constexpr int KVPAD  = 256;                // padded K for P@V GEMM
constexpr float LN_EPS = 1e-5f;
}

typedef __attribute__((ext_vector_type(8))) __bf16 bf16x8;
typedef __attribute__((ext_vector_type(4))) float  f32x4;

// ---------------- threefry2x32 gumbel (JAX jax.random.key(1)) ---------------
__device__ __forceinline__ unsigned rotl32(unsigned v, int d) {
  return (v << d) | (v >> (32 - d));
}

__device__ __forceinline__ float gumbel_noise(unsigned idx) {
  const unsigned ks0 = 0u, ks1 = 1u, ks2 = 0x1BD11BDBu;
  unsigned x0 = 0u + ks0;
  unsigned x1 = idx + ks1;
#define TFR(r) { x0 += x1; x1 = rotl32(x1, (r)); x1 ^= x0; }
  TFR(13) TFR(15) TFR(26) TFR(6)   x0 += ks1; x1 += ks2 + 1u;
  TFR(17) TFR(29) TFR(16) TFR(24)  x0 += ks2; x1 += ks0 + 2u;
  TFR(13) TFR(15) TFR(26) TFR(6)   x0 += ks0; x1 += ks1 + 3u;
  TFR(17) TFR(29) TFR(16) TFR(24)  x0 += ks1; x1 += ks2 + 4u;
  TFR(13) TFR(15) TFR(26) TFR(6)   x0 += ks2; x1 += ks0 + 5u;
#undef TFR
  unsigned bits = x0 ^ x1;
  float f = __uint_as_float((bits >> 9) | 0x3f800000u) - 1.0f;
  const float tiny = 1.17549435e-38f;
  float u = fmaxf(tiny, f + tiny);
  return -logf(-logf(u));
}

// ---------------- wave-level block reductions (256-thread blocks) -----------
__device__ __forceinline__ float block_sum(float v, float* red4) {
  const int lane = threadIdx.x & 63, wid = threadIdx.x >> 6;
  #pragma unroll
  for (int o = 32; o > 0; o >>= 1) v += __shfl_xor(v, o);
  if (lane == 0) red4[wid] = v;
  __syncthreads();
  const float r = red4[0] + red4[1] + red4[2] + red4[3];
  __syncthreads();
  return r;
}

__device__ __forceinline__ float block_max(float v, float* red4) {
  const int lane = threadIdx.x & 63, wid = threadIdx.x >> 6;
  #pragma unroll
  for (int o = 32; o > 0; o >>= 1) v = fmaxf(v, __shfl_xor(v, o));
  if (lane == 0) red4[wid] = v;
  __syncthreads();
  const float r = fmaxf(fmaxf(red4[0], red4[1]), fmaxf(red4[2], red4[3]));
  __syncthreads();
  return r;
}

// ---------------- async 16B global -> LDS ----------------------------------
__device__ __forceinline__ void async_copy16(const void* g, void* l) {
  __builtin_amdgcn_global_load_lds(
      (const __attribute__((address_space(1))) unsigned*)g,
      (__attribute__((address_space(3))) unsigned*)l, 16, 0, 0);
}

// ---------------- XCD-bijective swizzle (m204) ------------------------------
__device__ __forceinline__ int xcd_swizzle(int id, int nwg) {
  const int q = nwg >> 3, r = nwg & 7;
  const int xcd = id & 7, pos = id >> 3;
  return (xcd < r ? xcd * (q + 1) : r * (q + 1) + (xcd - r) * q) + pos;
}

// ---------------- 128^2 single-buffer MFMA GEMM (NT) + T2 swizzle -----------
// A: [M][K] bf16 (lda, batch stride sA); B: [N][K] bf16 (ldb, sB)
// C: f32 (STORE=0) or bf16 (STORE=1). Grid: x = tilesM*tilesN, y = batch
// (y also reusable as split-K index via sA/sB = k-offset, sC = buffer offset).
// LDS row-major [128][64]; data at (row, slot16B) is global
// (row, slot ^ (row&7)) via pre-swizzled global source (rule #21); ds_read
// applies the same XOR. Measured 0 bank conflicts (round 5+).
template<int STORE, bool GELU>
__global__ void mm_nt(
    const __hip_bfloat16* __restrict__ A, long sA, int lda,
    const __hip_bfloat16* __restrict__ B, long sB, int ldb,
    void* __restrict__ Cv, long sC, int ldc,
    int M, int N, int K, const float* __restrict__ bias) {
  __shared__ __hip_bfloat16 As[128 * 64];
  __shared__ __hip_bfloat16 Bs[128 * 64];
  const int bz = blockIdx.y;
  A += (long)bz * sA;
  B += (long)bz * sB;
  const int tilesN = (N + 127) >> 7;
  const int id = xcd_swizzle(blockIdx.x, gridDim.x);
  const int row0 = (id / tilesN) * 128, col0 = (id % tilesN) * 128;

  const int tid = threadIdx.x, lane = tid & 63, wid = tid >> 6;
  const int wr = (wid >> 1) * 64, wc = (wid & 1) * 64;
  const int fr = lane & 15;
  const int kh = lane >> 4;
  const int fsw = fr & 7;                 // read-side XOR key
  f32x4 acc[4][4] = {};

  const int elem = wid * 512 + lane * 8;  // linear elem in 128x64 tile chunk

  for (int k0 = 0; k0 < K; k0 += 64) {
    #pragma unroll
    for (int c = 0; c < 4; c++) {
      const int e = c * 2048 + elem;
      const int r = e >> 6;               // LDS row this lane's 16B lands in
      const int slot = (e >> 3) & 7;      // 16B slot within the row
      const int ksw = ((slot ^ (r & 7)) << 3);  // pre-swizzled source k
      async_copy16(A + (long)(row0 + r) * lda + k0 + ksw,
                   (char*)As + c * 4096 + wid * 1024);
    }
    #pragma unroll
    for (int c = 0; c < 4; c++) {
      const int e = c * 2048 + elem;
      const int r = e >> 6;
      const int slot = (e >> 3) & 7;
      const int ksw = ((slot ^ (r & 7)) << 3);
      async_copy16(B + (long)(col0 + r) * ldb + k0 + ksw,
                   (char*)Bs + c * 4096 + wid * 1024);
    }
    __syncthreads();
    #pragma unroll
    for (int ks = 0; ks < 2; ks++) {
      bf16x8 a[4], b[4];
      #pragma unroll
      for (int i = 0; i < 4; i++) {
        const int row = wr + i * 16 + fr;
        const int sl  = ((ks << 2) | kh) ^ fsw;   // swizzled slot
        a[i] = *(const bf16x8*)((const char*)As + row * 128 + (sl << 4));
      }
      #pragma unroll
      for (int j = 0; j < 4; j++) {
        const int row = wc + j * 16 + fr;
        const int sl  = ((ks << 2) | kh) ^ fsw;
        b[j] = *(const bf16x8*)((const char*)Bs + row * 128 + (sl << 4));
      }
      #pragma unroll
      for (int i = 0; i < 4; i++)
        #pragma unroll
        for (int j = 0; j < 4; j++)
          acc[i][j] = __builtin_amdgcn_mfma_f32_16x16x32_bf16(
              a[i], b[j], acc[i][j], 0, 0, 0);
    }
    __syncthreads();
  }

  // epilogue: D layout col = lane&15, row = (lane>>4)*4 + reg
  #pragma unroll
  for (int i = 0; i < 4; i++) {
    #pragma unroll
    for (int j = 0; j < 4; j++) {
      #pragma unroll
      for (int t = 0; t < 4; t++) {
        const int r  = row0 + wr + i * 16 + kh * 4 + t;
        const int cc = col0 + wc + j * 16 + fr;
        if (r < M && cc < N) {
          float v = acc[i][j][t];
          if (bias) v += bias[cc];
          if (GELU) v = 0.5f * v * (1.0f + erff(v * 0.70710678118654752f));
          if (STORE == 0)
            ((float*)Cv)[(long)bz * sC + (long)r * ldc + cc] = v;
          else
            ((__hip_bfloat16*)Cv)[(long)bz * sC + (long)r * ldc + cc] =
                __float2bfloat16(v);
        }
      }
    }
  }
}

// ---------------- f32 [K][N] -> bf16 [N][K] transpose (single matrix) -------
__global__ void transpose_bf16_kernel(const float* __restrict__ W,
                                      __hip_bfloat16* __restrict__ Wt,
                                      int K, int N) {
  __shared__ float t[32][33];
  const int k0 = blockIdx.x * 32, n0 = blockIdx.y * 32;
  const int tx = threadIdx.x & 31, ty = threadIdx.x >> 5;
  #pragma unroll
  for (int i = 0; i < 32; i += 8)
    t[ty + i][tx] = W[(long)(k0 + ty + i) * N + n0 + tx];
  __syncthreads();
  #pragma unroll
  for (int i = 0; i < 32; i += 8)
    Wt[(long)(n0 + ty + i) * K + k0 + tx] = __float2bfloat16(t[tx][ty + i]);
}

// ---------------- weight transpose, 64x64 tiles, y = layer ------------------
// Round-8 version (0 bank conflicts, HBM-bound at ~2.5 TB/s).
__global__ void wtrans_kernel(const float* __restrict__ Wq,
                              const float* __restrict__ Wk,
                              const float* __restrict__ Wv,
                              const float* __restrict__ W1,
                              const float* __restrict__ W2,
                              __hip_bfloat16* __restrict__ wqkv_t,
                              __hip_bfloat16* __restrict__ w1_t,
                              __hip_bfloat16* __restrict__ w2_t,
                              long sq, long s1, long s2) {
  __shared__ float t[64][65];
  const int l = blockIdx.y;
  Wq += (long)l * DIM * DIM;  Wk += (long)l * DIM * DIM;
  Wv += (long)l * DIM * DIM;
  W1 += (long)l * DIM * FF_DIM;  W2 += (long)l * FF_DIM * DIM;
  wqkv_t += (long)l * sq;  w1_t += (long)l * s1;  w2_t += (long)l * s2;

  const int id = blockIdx.x;
  const float* W; __hip_bfloat16* O; int K, N, k0, n0;
  if (id < 432) {                       // Wq/Wk/Wv: 3 x 12x12 tiles of 64
    const int m = id / 144, tt = id % 144;
    W = (m == 0) ? Wq : (m == 1) ? Wk : Wv;
    O = wqkv_t + (long)m * DIM * DIM;
    K = DIM; N = DIM; k0 = (tt / 12) * 64; n0 = (tt % 12) * 64;
  } else if (id < 1008) {               // W1 [768][3072]: 12x48 tiles
    const int tt = id - 432;
    W = W1; O = w1_t;
    K = DIM; N = FF_DIM; k0 = (tt / 48) * 64; n0 = (tt % 48) * 64;
  } else {                              // W2 [3072][768]: 48x12 tiles
    const int tt = id - 1008;
    W = W2; O = w2_t;
    K = FF_DIM; N = DIM; k0 = (tt / 12) * 64; n0 = (tt % 12) * 64;
  }
  const int tx = threadIdx.x & 63, ty = threadIdx.x >> 6;  // 64 x 4
  #pragma unroll
  for (int i = 0; i < 16; i++) {
    const int r = ty + i * 4;
    t[r][tx] = W[(long)(k0 + r) * N + n0 + tx];
  }
  __syncthreads();
  #pragma unroll
  for (int i = 0; i < 16; i++) {
    const int r = ty + i * 4;                    // output row (n)
    O[(long)(n0 + r) * K + k0 + tx] = __float2bfloat16(t[tx][r]);
  }
}

// ---------------- fused QKV bias, all layers, built once --------------------
__global__ void build_qkv_bias(const float* __restrict__ bq,
                               const float* __restrict__ bk,
                               const float* __restrict__ bv,
                               float* __restrict__ o) {
  const int l = blockIdx.x;
  for (int d = threadIdx.x; d < DIM; d += 256) {
    o[l * QKVN + d]           = bq[l * DIM + d];
    o[l * QKVN + DIM + d]     = bk[l * DIM + d];
    o[l * QKVN + 2 * DIM + d] = bv[l * DIM + d];
  }
}

// ---------------- V slice -> vt[b][d][tok] (tok padded to 256 w/ zeros) -----
__global__ void vtrans_kernel(const __hip_bfloat16* __restrict__ qkv,
                              __hip_bfloat16* __restrict__ vt) {
  __shared__ __hip_bfloat16 s[64][68];
  const int b = blockIdx.z;
  const int t0 = blockIdx.x * 64;
  const int d0 = blockIdx.y * 64;
  const int tx = threadIdx.x & 63, ty = threadIdx.x >> 6;  // 64 x 4
  for (int i = ty; i < 64; i += 4) {
    const int t = t0 + i;
    __hip_bfloat16 v = __float2bfloat16(0.f);
    if (t < NTOK) v = qkv[(long)(b * NTOK + t) * QKVN + 2 * DIM + d0 + tx];
    s[i][tx] = v;
  }
  __syncthreads();
  for (int i = ty; i < 64; i += 4)
    vt[((long)b * DIM + d0 + i) * KVPAD + t0 + tx] = s[tx][i];
}

// ---------------- patch embedding helpers -----------------------------------
__global__ void im2col_kernel(const float* __restrict__ x,
                              __hip_bfloat16* __restrict__ col) {
  const int p = blockIdx.x;
  const int b = p / NPATCH, pi = p % NPATCH;
  const int h = pi / 14, w = pi % 14;
  for (int e = threadIdx.x; e < DIM; e += 256) {
    const int c = e >> 8, r = e & 255, pp = r >> 4, q = r & 15;
    col[(long)p * DIM + e] = __float2bfloat16(
        x[(((long)b * 3 + c) * 224 + h * 16 + pp) * 224 + w * 16 + q]);
  }
}

__global__ void assemble_kernel(const float* __restrict__ tmp,
                                const float* __restrict__ cls,
                                const float* __restrict__ pos,
                                float* __restrict__ tok,
                                __hip_bfloat16* __restrict__ tok_bf) {
  const int row = blockIdx.x;
  const int b = row / NTOK, n = row % NTOK;
  for (int d = threadIdx.x; d < DIM; d += 256) {
    float v = (n == 0) ? cls[d] : tmp[(long)(b * NPATCH + n - 1) * DIM + d];
    v += pos[n * DIM + d];
    tok[(long)row * DIM + d] = v;
    tok_bf[(long)row * DIM + d] = __float2bfloat16(v);
  }
}

// ---------------- fused gumbel + softmax (per q-row block) ------------------
__global__ void softmax_kernel(const float* __restrict__ sc,
                               __hip_bfloat16* __restrict__ P, int layer) {
  __shared__ float red[4];
  const int row = blockIdx.x;
  const int b = row / NTOK, n = row % NTOK;
  const int tid = threadIdx.x;
  const long base = (long)row * NTOK;
  const float inv_sqrt_d = 0.036084391824351615f;

  float x = -INFINITY;
  if (tid < NTOK) {
    const unsigned idx =
        ((((unsigned)layer * NBATCH + b) * NTOK + n) * NTOK) + tid;
    x = sc[base + tid] * inv_sqrt_d + gumbel_noise(idx);
  }
  const float mx = block_max(x, red);
  float ex = (tid < NTOK) ? expf(x - mx) : 0.f;
  const float s = block_sum(ex, red);
  const float pv = (tid < NTOK) ? ex / s : 0.f;
  P[(long)row * KVPAD + tid] = __float2bfloat16(pv);
}

// ---------------- residual add (1-2 partials + opt bias) + LayerNorm --------
__global__ void add_ln_kernel(float* __restrict__ tok,
                              __hip_bfloat16* __restrict__ tok_bf,
                              const float* __restrict__ res,
                              const float* __restrict__ res2,
                              const float* __restrict__ rbias,
                              const float* __restrict__ g,
                              const float* __restrict__ beta) {
  __shared__ float red[4];
  const int row = blockIdx.x;
  const int tid = threadIdx.x;
  const long base = (long)row * DIM;
  float v[3];
  float s = 0.f;
  #pragma unroll
  for (int i = 0; i < 3; i++) {
    const int d = tid + (i << 8);
    float r = tok[base + d] + res[base + d];
    if (res2)  r += res2[base + d];
    if (rbias) r += rbias[d];
    v[i] = r;
    s += r;
  }
  const float mean = block_sum(s, red) * (1.0f / DIM);
  float s2 = 0.f;
  #pragma unroll
  for (int i = 0; i < 3; i++) { const float dd = v[i] - mean; s2 += dd * dd; }
  const float var = block_sum(s2, red) * (1.0f / DIM);
  const float inv = 1.0f / sqrtf(var + LN_EPS);
  #pragma unroll
  for (int i = 0; i < 3; i++) {
    const int d = tid + (i << 8);
    const float o = (v[i] - mean) * inv * g[d] + beta[d];
    tok[base + d] = o;
    tok_bf[base + d] = __float2bfloat16(o);
  }
}

// ---------------- final LN (cls row) + head ---------------------------------
__global__ void head_kernel(const float* __restrict__ tok,
                            const float* __restrict__ g,
                            const float* __restrict__ beta,
                            const float* __restrict__ hw,
                            const float* __restrict__ hb,
                            float* __restrict__ out) {
  __shared__ float red[4];
  __shared__ float xn[DIM];
  const int b = blockIdx.x;
  const int tid = threadIdx.x;
  const float* xr = tok + (long)b * NTOK * DIM;
  float v[3];
  float s = 0.f;
  #pragma unroll
  for (int i = 0; i < 3; i++) { v[i] = xr[tid + (i << 8)]; s += v[i]; }
  const float mean = block_sum(s, red) * (1.0f / DIM);
  float s2 = 0.f;
  #pragma unroll
  for (int i = 0; i < 3; i++) { const float dd = v[i] - mean; s2 += dd * dd; }
  const float var = block_sum(s2, red) * (1.0f / DIM);
  const float inv = 1.0f / sqrtf(var + LN_EPS);
  #pragma unroll
  for (int i = 0; i < 3; i++) {
    const int d = tid + (i << 8);
    xn[d] = (v[i] - mean) * inv * g[d] + beta[d];
  }
  __syncthreads();
  for (int c = tid; c < 100; c += 256) {
    float acc = hb[c];
    for (int d = 0; d < DIM; d++) acc += xn[d] * hw[d * 100 + c];
    out[b * 100 + c] = acc;
  }
}

// ---------------------------------------------------------------------------
extern "C" void kernel_launch(void* const* d_in, const int* in_sizes, int n_in,
                              void* d_out, int out_size, void* d_ws, size_t ws_size,
                              hipStream_t stream) {
  const float* x        = (const float*)d_in[0];
  const float* patch_w  = (const float*)d_in[1];
  const float* patch_b  = (const float*)d_in[2];
  const float* cls_tok  = (const float*)d_in[3];
  const float* pos_emb  = (const float*)d_in[4];
  const float* Wq       = (const float*)d_in[5];
  const float* bq       = (const float*)d_in[6];
  const float* Wk       = (const float*)d_in[7];
  const float* bk       = (const float*)d_in[8];
  const float* Wv       = (const float*)d_in[9];
  const float* bv       = (const float*)d_in[10];
  const float* W1       = (const float*)d_in[11];
  const float* b1       = (const float*)d_in[12];
  const float* W2       = (const float*)d_in[13];
  const float* b2       = (const float*)d_in[14];
  const float* ln1_g    = (const float*)d_in[15];
  const float* ln1_b    = (const float*)d_in[16];
  const float* ln2_g    = (const float*)d_in[17];
  const float* ln2_b    = (const float*)d_in[18];
  const float* lnf_g    = (const float*)d_in[19];
  const float* lnf_b    = (const float*)d_in[20];
  const float* head_w   = (const float*)d_in[21];
  const float* head_b   = (const float*)d_in[22];
  float* out = (float*)d_out;

  // per-layer transposed-weight sizes (bf16 elems)
  const long WQKV = (long)QKVN * DIM;
  const long W1SZ = (long)FF_DIM * DIM;
  const long W2SZ = (long)DIM * FF_DIM;
  const long WLAYER = WQKV + W1SZ + W2SZ;

  const long F32N = 3L * 6400 * DIM + (long)NLAYER * QKVN;
  const long BF16FIX = 6400L * DIM + 6400L * FF_DIM +
                       (long)NBATCH * DIM * KVPAD + 6400L * KVPAD +
                       (long)DIM * DIM;
  const size_t need12 = (size_t)F32N * 4 + (size_t)(BF16FIX + 12 * WLAYER) * 2;
  const bool hoist = ws_size >= need12;
  const int NW = hoist ? NLAYER : 1;

  // ---- workspace layout ----
  float* fb = (float*)d_ws;
  long fo = 0;
  float* tok      = fb + fo; fo += 6400L * DIM;
  float* b4       = fb + fo; fo += 6400L * DIM;
  float* b4b      = fb + fo; fo += 6400L * DIM;      // FF2 split-K partial 1
  float* bias_all = fb + fo; fo += (long)NLAYER * QKVN;
  __hip_bfloat16* hbuf = (__hip_bfloat16*)(fb + fo);
  long ho = 0;
  __hip_bfloat16* tok_bf = hbuf + ho; ho += 6400L * DIM;
  __hip_bfloat16* qkv    = hbuf + ho;                // alias with ffout head
  __hip_bfloat16* ffout  = hbuf + ho; ho += 6400L * FF_DIM;
  // scores f32 aliases the ffout TAIL (beyond qkv's 6400*2304 bf16 elems)
  float* scbuf = (float*)(qkv + 6400L * QKVN);
  __hip_bfloat16* vt     = hbuf + ho; ho += (long)NBATCH * DIM * KVPAD;
  __hip_bfloat16* Pb     = hbuf + ho; ho += 6400L * KVPAD;
  __hip_bfloat16* pw_t   = hbuf + ho; ho += (long)DIM * DIM;
  __hip_bfloat16* wqkv_t = hbuf + ho; ho += (long)NW * WQKV;
  __hip_bfloat16* w1_t   = hbuf + ho; ho += (long)NW * W1SZ;
  __hip_bfloat16* w2_t   = hbuf + ho; ho += (long)NW * W2SZ;

  const long DD = (long)DIM * DIM;
  const long QKVSTRIDE = (long)NTOK * QKVN;
  const long TOKSTRIDE = (long)NTOK * DIM;
  const long SCSTRIDE  = (long)NTOK * NTOK;
  const long VTSTRIDE  = (long)DIM * KVPAD;
  const long PSTRIDE   = (long)NTOK * KVPAD;

  build_qkv_bias<<<NLAYER, 256, 0, stream>>>(bq, bk, bv, bias_all);

  // hoisted all-layer weight transpose (one dispatch) if ws permits
  if (hoist) {
    wtrans_kernel<<<dim3(1584, NLAYER), 256, 0, stream>>>(
        Wq, Wk, Wv, W1, W2, wqkv_t, w1_t, w2_t, WQKV, W1SZ, W2SZ);
  }

  // ---- patch embedding ----
  im2col_kernel<<<PROWS, 256, 0, stream>>>(x, ffout);
  transpose_bf16_kernel<<<dim3(DIM / 32, DIM / 32), 256, 0, stream>>>(
      patch_w, pw_t, DIM, DIM);
  mm_nt<0, false><<<dim3(49 * 6, 1), 256, 0, stream>>>(
      ffout, 0, DIM, pw_t, 0, DIM, b4, 0, DIM, PROWS, DIM, DIM, patch_b);
  assemble_kernel<<<ROWS, 256, 0, stream>>>(b4, cls_tok, pos_emb, tok, tok_bf);

  for (int l = 0; l < NLAYER; l++) {
    __hip_bfloat16* wqkv_l = wqkv_t + (hoist ? (long)l * WQKV : 0);
    __hip_bfloat16* w1_l   = w1_t   + (hoist ? (long)l * W1SZ : 0);
    __hip_bfloat16* w2_l   = w2_t   + (hoist ? (long)l * W2SZ : 0);
    if (!hoist) {
      wtrans_kernel<<<dim3(1584, 1), 256, 0, stream>>>(
          Wq + l * DD, Wk + l * DD, Wv + l * DD,
          W1 + (long)l * DIM * FF_DIM, W2 + (long)l * FF_DIM * DIM,
          wqkv_l, w1_l, w2_l, 0, 0, 0);
    }

    // fused QKV: [6304][2304] = tok_bf @ wqkv^T + bias
    mm_nt<1, false><<<dim3(50 * (QKVN / 128), 1), 256, 0, stream>>>(
        tok_bf, 0, DIM, wqkv_l, 0, DIM, qkv, 0, QKVN,
        ROWS, QKVN, DIM, bias_all + l * QKVN);

    // V slice -> vt[b][d][tok] (zero-padded tok 197..255)
    vtrans_kernel<<<dim3(KVPAD / 64, DIM / 64, NBATCH), 256, 0, stream>>>(qkv, vt);

    // scores = Q @ K^T (f32 -> scbuf), Q/K are lda=2304 slices of qkv
    mm_nt<0, false><<<dim3(2 * 2, NBATCH), 256, 0, stream>>>(
        qkv, QKVSTRIDE, QKVN, qkv + DIM, QKVSTRIDE, QKVN, scbuf, SCSTRIDE, NTOK,
        NTOK, NTOK, DIM, nullptr);

    // gumbel + softmax (6304 blocks -> full TLP for the VALU-heavy phase)
    softmax_kernel<<<ROWS, 256, 0, stream>>>(scbuf, Pb, l);

    // attn = P @ V   (NT with B = vt, K = KVPAD=256 zero-padded)
    mm_nt<0, false><<<dim3(2 * (DIM / 128), NBATCH), 256, 0, stream>>>(
        Pb, PSTRIDE, KVPAD, vt, VTSTRIDE, KVPAD, b4, TOKSTRIDE, DIM,
        NTOK, DIM, KVPAD, nullptr);

    add_ln_kernel<<<ROWS, 256, 0, stream>>>(tok, tok_bf, b4, nullptr, nullptr,
        ln1_g + l * DIM, ln1_b + l * DIM);

    // FF1 (+bias+GELU, bf16 out); ffout overwrites qkv + scbuf (both dead)
    mm_nt<1, true><<<dim3(50 * (FF_DIM / 128), 1), 256, 0, stream>>>(
        tok_bf, 0, DIM, w1_l, 0, DIM, ffout, 0, FF_DIM,
        ROWS, FF_DIM, DIM, b1 + l * FF_DIM);

    // FF2 split-K=2 via batch-stride trick: y = k-half; partials b4, b4b.
    mm_nt<0, false><<<dim3(50 * (DIM / 128), 2), 256, 0, stream>>>(
        ffout, 1536, FF_DIM, w2_l, 1536, FF_DIM,
        b4, 6400L * DIM, DIM, ROWS, DIM, 1536, nullptr);

    // LN2 folds partial sum + b2 bias
    add_ln_kernel<<<ROWS, 256, 0, stream>>>(tok, tok_bf, b4, b4b, b2 + l * DIM,
        ln2_g + l * DIM, ln2_b + l * DIM);
  }

  head_kernel<<<NBATCH, 256, 0, stream>>>(tok, lnf_g, lnf_b, head_w, head_b, out);
}

// Round 14
// 2836.418 us; speedup vs baseline: 1.0410x; 1.0176x over previous
//
#include <hip/hip_runtime.h>
#include <hip/hip_bf16.h>
#include <math.h>

// ---------------------------------------------------------------------------
// ViT forward (B=32, N=197, D=768, FF=3072, 12 layers) — round 14:
// Base = round 13 (confirmed best, 2886 us). ONLY change: vectorize the two
// transpose kernels' global memory access (they were 2 B/lane stores):
// - wtrans: float4 global loads + scalar LDS writes (stride-65 rows -> 2-way
//   banks, free) + ushort4 packed stores (8 B/lane). R9's conflicts came from
//   VECTOR LDS writes; scalar writes avoid that.
// - vtrans: uint2 global loads + scalar LDS writes into s[64][70] (stride 70
//   -> transposed column reads 2-way) + uint2 global stores.
// GEMM core / attention / reductions byte-identical to round 13.
// ---------------------------------------------------------------------------

namespace {
constexpr int DIM    = 768;
constexpr int FF_DIM = 3072;
constexpr int QKVN   = 2304;               // 3*DIM fused QKV output width
constexpr int NTOK   = 197;
constexpr int NBATCH = 32;
constexpr int NLAYER = 12;
constexpr int ROWS   = NBATCH * NTOK;      // 6304
constexpr int NPATCH = 196;
constexpr int PROWS  = NBATCH * NPATCH;    // 6272
constexpr int KVPAD  = 256;                // padded K for P@V GEMM
constexpr float LN_EPS = 1e-5f;
}

typedef __attribute__((ext_vector_type(8))) __bf16 bf16x8;
typedef __attribute__((ext_vector_type(4))) float  f32x4;

// ---------------- threefry2x32 gumbel (JAX jax.random.key(1)) ---------------
__device__ __forceinline__ unsigned rotl32(unsigned v, int d) {
  return (v << d) | (v >> (32 - d));
}

__device__ __forceinline__ float gumbel_noise(unsigned idx) {
  const unsigned ks0 = 0u, ks1 = 1u, ks2 = 0x1BD11BDBu;
  unsigned x0 = 0u + ks0;
  unsigned x1 = idx + ks1;
#define TFR(r) { x0 += x1; x1 = rotl32(x1, (r)); x1 ^= x0; }
  TFR(13) TFR(15) TFR(26) TFR(6)   x0 += ks1; x1 += ks2 + 1u;
  TFR(17) TFR(29) TFR(16) TFR(24)  x0 += ks2; x1 += ks0 + 2u;
  TFR(13) TFR(15) TFR(26) TFR(6)   x0 += ks0; x1 += ks1 + 3u;
  TFR(17) TFR(29) TFR(16) TFR(24)  x0 += ks1; x1 += ks2 + 4u;
  TFR(13) TFR(15) TFR(26) TFR(6)   x0 += ks2; x1 += ks0 + 5u;
#undef TFR
  unsigned bits = x0 ^ x1;
  float f = __uint_as_float((bits >> 9) | 0x3f800000u) - 1.0f;
  const float tiny = 1.17549435e-38f;
  float u = fmaxf(tiny, f + tiny);
  return -logf(-logf(u));
}

// ---------------- wave-level block reductions (256-thread blocks) -----------
__device__ __forceinline__ float block_sum(float v, float* red4) {
  const int lane = threadIdx.x & 63, wid = threadIdx.x >> 6;
  #pragma unroll
  for (int o = 32; o > 0; o >>= 1) v += __shfl_xor(v, o);
  if (lane == 0) red4[wid] = v;
  __syncthreads();
  const float r = red4[0] + red4[1] + red4[2] + red4[3];
  __syncthreads();
  return r;
}

__device__ __forceinline__ float block_max(float v, float* red4) {
  const int lane = threadIdx.x & 63, wid = threadIdx.x >> 6;
  #pragma unroll
  for (int o = 32; o > 0; o >>= 1) v = fmaxf(v, __shfl_xor(v, o));
  if (lane == 0) red4[wid] = v;
  __syncthreads();
  const float r = fmaxf(fmaxf(red4[0], red4[1]), fmaxf(red4[2], red4[3]));
  __syncthreads();
  return r;
}

// ---------------- async 16B global -> LDS ----------------------------------
__device__ __forceinline__ void async_copy16(const void* g, void* l) {
  __builtin_amdgcn_global_load_lds(
      (const __attribute__((address_space(1))) unsigned*)g,
      (__attribute__((address_space(3))) unsigned*)l, 16, 0, 0);
}

// ---------------- XCD-bijective swizzle (m204) ------------------------------
__device__ __forceinline__ int xcd_swizzle(int id, int nwg) {
  const int q = nwg >> 3, r = nwg & 7;
  const int xcd = id & 7, pos = id >> 3;
  return (xcd < r ? xcd * (q + 1) : r * (q + 1) + (xcd - r) * q) + pos;
}

// ---------------- 128^2 single-buffer MFMA GEMM (NT) + T2 swizzle -----------
// A: [M][K] bf16 (lda, batch stride sA); B: [N][K] bf16 (ldb, sB)
// C: f32 (STORE=0) or bf16 (STORE=1). Grid: x = tilesM*tilesN, y = batch
// (y also reusable as split-K index via sA/sB = k-offset, sC = buffer offset).
// LDS row-major [128][64]; data at (row, slot16B) is global
// (row, slot ^ (row&7)) via pre-swizzled global source (rule #21); ds_read
// applies the same XOR. Measured 0 bank conflicts (round 5+).
template<int STORE, bool GELU>
__global__ void mm_nt(
    const __hip_bfloat16* __restrict__ A, long sA, int lda,
    const __hip_bfloat16* __restrict__ B, long sB, int ldb,
    void* __restrict__ Cv, long sC, int ldc,
    int M, int N, int K, const float* __restrict__ bias) {
  __shared__ __hip_bfloat16 As[128 * 64];
  __shared__ __hip_bfloat16 Bs[128 * 64];
  const int bz = blockIdx.y;
  A += (long)bz * sA;
  B += (long)bz * sB;
  const int tilesN = (N + 127) >> 7;
  const int id = xcd_swizzle(blockIdx.x, gridDim.x);
  const int row0 = (id / tilesN) * 128, col0 = (id % tilesN) * 128;

  const int tid = threadIdx.x, lane = tid & 63, wid = tid >> 6;
  const int wr = (wid >> 1) * 64, wc = (wid & 1) * 64;
  const int fr = lane & 15;
  const int kh = lane >> 4;
  const int fsw = fr & 7;                 // read-side XOR key
  f32x4 acc[4][4] = {};

  const int elem = wid * 512 + lane * 8;  // linear elem in 128x64 tile chunk

  for (int k0 = 0; k0 < K; k0 += 64) {
    #pragma unroll
    for (int c = 0; c < 4; c++) {
      const int e = c * 2048 + elem;
      const int r = e >> 6;               // LDS row this lane's 16B lands in
      const int slot = (e >> 3) & 7;      // 16B slot within the row
      const int ksw = ((slot ^ (r & 7)) << 3);  // pre-swizzled source k
      async_copy16(A + (long)(row0 + r) * lda + k0 + ksw,
                   (char*)As + c * 4096 + wid * 1024);
    }
    #pragma unroll
    for (int c = 0; c < 4; c++) {
      const int e = c * 2048 + elem;
      const int r = e >> 6;
      const int slot = (e >> 3) & 7;
      const int ksw = ((slot ^ (r & 7)) << 3);
      async_copy16(B + (long)(col0 + r) * ldb + k0 + ksw,
                   (char*)Bs + c * 4096 + wid * 1024);
    }
    __syncthreads();
    #pragma unroll
    for (int ks = 0; ks < 2; ks++) {
      bf16x8 a[4], b[4];
      #pragma unroll
      for (int i = 0; i < 4; i++) {
        const int row = wr + i * 16 + fr;
        const int sl  = ((ks << 2) | kh) ^ fsw;   // swizzled slot
        a[i] = *(const bf16x8*)((const char*)As + row * 128 + (sl << 4));
      }
      #pragma unroll
      for (int j = 0; j < 4; j++) {
        const int row = wc + j * 16 + fr;
        const int sl  = ((ks << 2) | kh) ^ fsw;
        b[j] = *(const bf16x8*)((const char*)Bs + row * 128 + (sl << 4));
      }
      #pragma unroll
      for (int i = 0; i < 4; i++)
        #pragma unroll
        for (int j = 0; j < 4; j++)
          acc[i][j] = __builtin_amdgcn_mfma_f32_16x16x32_bf16(
              a[i], b[j], acc[i][j], 0, 0, 0);
    }
    __syncthreads();
  }

  // epilogue: D layout col = lane&15, row = (lane>>4)*4 + reg
  #pragma unroll
  for (int i = 0; i < 4; i++) {
    #pragma unroll
    for (int j = 0; j < 4; j++) {
      #pragma unroll
      for (int t = 0; t < 4; t++) {
        const int r  = row0 + wr + i * 16 + kh * 4 + t;
        const int cc = col0 + wc + j * 16 + fr;
        if (r < M && cc < N) {
          float v = acc[i][j][t];
          if (bias) v += bias[cc];
          if (GELU) v = 0.5f * v * (1.0f + erff(v * 0.70710678118654752f));
          if (STORE == 0)
            ((float*)Cv)[(long)bz * sC + (long)r * ldc + cc] = v;
          else
            ((__hip_bfloat16*)Cv)[(long)bz * sC + (long)r * ldc + cc] =
                __float2bfloat16(v);
        }
      }
    }
  }
}

// ---------------- f32 [K][N] -> bf16 [N][K] transpose (single matrix) -------
__global__ void transpose_bf16_kernel(const float* __restrict__ W,
                                      __hip_bfloat16* __restrict__ Wt,
                                      int K, int N) {
  __shared__ float t[32][33];
  const int k0 = blockIdx.x * 32, n0 = blockIdx.y * 32;
  const int tx = threadIdx.x & 31, ty = threadIdx.x >> 5;
  #pragma unroll
  for (int i = 0; i < 32; i += 8)
    t[ty + i][tx] = W[(long)(k0 + ty + i) * N + n0 + tx];
  __syncthreads();
  #pragma unroll
  for (int i = 0; i < 32; i += 8)
    Wt[(long)(n0 + ty + i) * K + k0 + tx] = __float2bfloat16(t[tx][ty + i]);
}

// ---------------- weight transpose, 64x64 tiles, y = layer ------------------
// float4 global loads (16 B/lane) + SCALAR LDS writes (stride-65 rows:
// bank(65r+4j+u) = (r+4j+u)%32 -> 2-way, free); ushort4 packed stores
// (8 B/lane) from scalar LDS reads (bank(65(4j+u)+r) = (4j+u+r)%32 -> 2-way).
__global__ void wtrans_kernel(const float* __restrict__ Wq,
                              const float* __restrict__ Wk,
                              const float* __restrict__ Wv,
                              const float* __restrict__ W1,
                              const float* __restrict__ W2,
                              __hip_bfloat16* __restrict__ wqkv_t,
                              __hip_bfloat16* __restrict__ w1_t,
                              __hip_bfloat16* __restrict__ w2_t,
                              long sq, long s1, long s2) {
  __shared__ float t[64][65];
  const int l = blockIdx.y;
  Wq += (long)l * DIM * DIM;  Wk += (long)l * DIM * DIM;
  Wv += (long)l * DIM * DIM;
  W1 += (long)l * DIM * FF_DIM;  W2 += (long)l * FF_DIM * DIM;
  wqkv_t += (long)l * sq;  w1_t += (long)l * s1;  w2_t += (long)l * s2;

  const int id = blockIdx.x;
  const float* W; __hip_bfloat16* O; int K, N, k0, n0;
  if (id < 432) {                       // Wq/Wk/Wv: 3 x 12x12 tiles of 64
    const int m = id / 144, tt = id % 144;
    W = (m == 0) ? Wq : (m == 1) ? Wk : Wv;
    O = wqkv_t + (long)m * DIM * DIM;
    K = DIM; N = DIM; k0 = (tt / 12) * 64; n0 = (tt % 12) * 64;
  } else if (id < 1008) {               // W1 [768][3072]: 12x48 tiles
    const int tt = id - 432;
    W = W1; O = w1_t;
    K = DIM; N = FF_DIM; k0 = (tt / 48) * 64; n0 = (tt % 48) * 64;
  } else {                              // W2 [3072][768]: 48x12 tiles
    const int tt = id - 1008;
    W = W2; O = w2_t;
    K = FF_DIM; N = DIM; k0 = (tt / 12) * 64; n0 = (tt % 12) * 64;
  }
  const int j  = threadIdx.x & 15;      // quad index within a row
  const int ry = threadIdx.x >> 4;      // 0..15 rows per pass
  // load: float4 per lane, scalar LDS writes
  #pragma unroll
  for (int p = 0; p < 4; p++) {
    const int r = p * 16 + ry;          // input row k (0..63)
    const float4 v = *(const float4*)&W[(long)(k0 + r) * N + n0 + j * 4];
    t[r][j * 4 + 0] = v.x;
    t[r][j * 4 + 1] = v.y;
    t[r][j * 4 + 2] = v.z;
    t[r][j * 4 + 3] = v.w;
  }
  __syncthreads();
  // store: scalar LDS reads (transposed), ushort4 packed 8B global store
  #pragma unroll
  for (int p = 0; p < 4; p++) {
    const int r = p * 16 + ry;          // output row n (0..63)
    union { __hip_bfloat16 h[4]; uint2 u2; } pk;
    #pragma unroll
    for (int u = 0; u < 4; u++)
      pk.h[u] = __float2bfloat16(t[j * 4 + u][r]);
    *(uint2*)&O[(long)(n0 + r) * K + k0 + j * 4] = pk.u2;
  }
}

// ---------------- fused QKV bias, all layers, built once --------------------
__global__ void build_qkv_bias(const float* __restrict__ bq,
                               const float* __restrict__ bk,
                               const float* __restrict__ bv,
                               float* __restrict__ o) {
  const int l = blockIdx.x;
  for (int d = threadIdx.x; d < DIM; d += 256) {
    o[l * QKVN + d]           = bq[l * DIM + d];
    o[l * QKVN + DIM + d]     = bk[l * DIM + d];
    o[l * QKVN + 2 * DIM + d] = bv[l * DIM + d];
  }
}

// ---------------- V slice -> vt[b][d][tok] (tok padded to 256 w/ zeros) -----
// uint2 global loads (8 B/lane) + scalar LDS writes; scalar LDS reads
// (s[64][70]: stride 35 dwords -> transposed column reads bank 12j%32 ->
// 2-way) + uint2 global stores (8 B/lane; all addresses 8B-aligned:
// KVPAD rows = 512 B, QKVN rows = 4608 B, offsets multiples of 8 B).
__global__ void vtrans_kernel(const __hip_bfloat16* __restrict__ qkv,
                              __hip_bfloat16* __restrict__ vt) {
  __shared__ __hip_bfloat16 s[64][70];
  const int b = blockIdx.z;
  const int t0 = blockIdx.x * 64;       // token tile base
  const int d0 = blockIdx.y * 64;       // dim tile base
  const int j  = threadIdx.x & 15;      // quad index
  const int ry = threadIdx.x >> 4;      // 0..15

  // load: s[tok][d] <- qkv[b][t0+tok][2*DIM + d0 + d], 4 bf16 per lane
  #pragma unroll
  for (int p = 0; p < 4; p++) {
    const int t = t0 + p * 16 + ry;
    union { uint2 u2; __hip_bfloat16 h[4]; } pk;
    if (t < NTOK) {
      pk.u2 = *(const uint2*)&qkv[(long)(b * NTOK + t) * QKVN +
                                  2 * DIM + d0 + j * 4];
    } else {
      pk.u2.x = 0u; pk.u2.y = 0u;       // bf16 zeros (K-padding)
    }
    #pragma unroll
    for (int u = 0; u < 4; u++) s[p * 16 + ry][j * 4 + u] = pk.h[u];
  }
  __syncthreads();
  // store: vt[b][d0+d][t0 + 4j .. +3] <- s[4j..4j+3][d], 4 bf16 per lane
  #pragma unroll
  for (int p = 0; p < 4; p++) {
    const int d = p * 16 + ry;
    union { __hip_bfloat16 h[4]; uint2 u2; } pk;
    #pragma unroll
    for (int u = 0; u < 4; u++) pk.h[u] = s[j * 4 + u][d];
    *(uint2*)&vt[((long)b * DIM + d0 + d) * KVPAD + t0 + j * 4] = pk.u2;
  }
}

// ---------------- patch embedding helpers -----------------------------------
__global__ void im2col_kernel(const float* __restrict__ x,
                              __hip_bfloat16* __restrict__ col) {
  const int p = blockIdx.x;
  const int b = p / NPATCH, pi = p % NPATCH;
  const int h = pi / 14, w = pi % 14;
  for (int e = threadIdx.x; e < DIM; e += 256) {
    const int c = e >> 8, r = e & 255, pp = r >> 4, q = r & 15;
    col[(long)p * DIM + e] = __float2bfloat16(
        x[(((long)b * 3 + c) * 224 + h * 16 + pp) * 224 + w * 16 + q]);
  }
}

__global__ void assemble_kernel(const float* __restrict__ tmp,
                                const float* __restrict__ cls,
                                const float* __restrict__ pos,
                                float* __restrict__ tok,
                                __hip_bfloat16* __restrict__ tok_bf) {
  const int row = blockIdx.x;
  const int b = row / NTOK, n = row % NTOK;
  for (int d = threadIdx.x; d < DIM; d += 256) {
    float v = (n == 0) ? cls[d] : tmp[(long)(b * NPATCH + n - 1) * DIM + d];
    v += pos[n * DIM + d];
    tok[(long)row * DIM + d] = v;
    tok_bf[(long)row * DIM + d] = __float2bfloat16(v);
  }
}

// ---------------- fused gumbel + softmax (per q-row block) ------------------
__global__ void softmax_kernel(const float* __restrict__ sc,
                               __hip_bfloat16* __restrict__ P, int layer) {
  __shared__ float red[4];
  const int row = blockIdx.x;
  const int b = row / NTOK, n = row % NTOK;
  const int tid = threadIdx.x;
  const long base = (long)row * NTOK;
  const float inv_sqrt_d = 0.036084391824351615f;

  float x = -INFINITY;
  if (tid < NTOK) {
    const unsigned idx =
        ((((unsigned)layer * NBATCH + b) * NTOK + n) * NTOK) + tid;
    x = sc[base + tid] * inv_sqrt_d + gumbel_noise(idx);
  }
  const float mx = block_max(x, red);
  float ex = (tid < NTOK) ? expf(x - mx) : 0.f;
  const float s = block_sum(ex, red);
  const float pv = (tid < NTOK) ? ex / s : 0.f;
  P[(long)row * KVPAD + tid] = __float2bfloat16(pv);
}

// ---------------- residual add (1-2 partials + opt bias) + LayerNorm --------
__global__ void add_ln_kernel(float* __restrict__ tok,
                              __hip_bfloat16* __restrict__ tok_bf,
                              const float* __restrict__ res,
                              const float* __restrict__ res2,
                              const float* __restrict__ rbias,
                              const float* __restrict__ g,
                              const float* __restrict__ beta) {
  __shared__ float red[4];
  const int row = blockIdx.x;
  const int tid = threadIdx.x;
  const long base = (long)row * DIM;
  float v[3];
  float s = 0.f;
  #pragma unroll
  for (int i = 0; i < 3; i++) {
    const int d = tid + (i << 8);
    float r = tok[base + d] + res[base + d];
    if (res2)  r += res2[base + d];
    if (rbias) r += rbias[d];
    v[i] = r;
    s += r;
  }
  const float mean = block_sum(s, red) * (1.0f / DIM);
  float s2 = 0.f;
  #pragma unroll
  for (int i = 0; i < 3; i++) { const float dd = v[i] - mean; s2 += dd * dd; }
  const float var = block_sum(s2, red) * (1.0f / DIM);
  const float inv = 1.0f / sqrtf(var + LN_EPS);
  #pragma unroll
  for (int i = 0; i < 3; i++) {
    const int d = tid + (i << 8);
    const float o = (v[i] - mean) * inv * g[d] + beta[d];
    tok[base + d] = o;
    tok_bf[base + d] = __float2bfloat16(o);
  }
}

// ---------------- final LN (cls row) + head ---------------------------------
__global__ void head_kernel(const float* __restrict__ tok,
                            const float* __restrict__ g,
                            const float* __restrict__ beta,
                            const float* __restrict__ hw,
                            const float* __restrict__ hb,
                            float* __restrict__ out) {
  __shared__ float red[4];
  __shared__ float xn[DIM];
  const int b = blockIdx.x;
  const int tid = threadIdx.x;
  const float* xr = tok + (long)b * NTOK * DIM;
  float v[3];
  float s = 0.f;
  #pragma unroll
  for (int i = 0; i < 3; i++) { v[i] = xr[tid + (i << 8)]; s += v[i]; }
  const float mean = block_sum(s, red) * (1.0f / DIM);
  float s2 = 0.f;
  #pragma unroll
  for (int i = 0; i < 3; i++) { const float dd = v[i] - mean; s2 += dd * dd; }
  const float var = block_sum(s2, red) * (1.0f / DIM);
  const float inv = 1.0f / sqrtf(var + LN_EPS);
  #pragma unroll
  for (int i = 0; i < 3; i++) {
    const int d = tid + (i << 8);
    xn[d] = (v[i] - mean) * inv * g[d] + beta[d];
  }
  __syncthreads();
  for (int c = tid; c < 100; c += 256) {
    float acc = hb[c];
    for (int d = 0; d < DIM; d++) acc += xn[d] * hw[d * 100 + c];
    out[b * 100 + c] = acc;
  }
}

// ---------------------------------------------------------------------------
extern "C" void kernel_launch(void* const* d_in, const int* in_sizes, int n_in,
                              void* d_out, int out_size, void* d_ws, size_t ws_size,
                              hipStream_t stream) {
  const float* x        = (const float*)d_in[0];
  const float* patch_w  = (const float*)d_in[1];
  const float* patch_b  = (const float*)d_in[2];
  const float* cls_tok  = (const float*)d_in[3];
  const float* pos_emb  = (const float*)d_in[4];
  const float* Wq       = (const float*)d_in[5];
  const float* bq       = (const float*)d_in[6];
  const float* Wk       = (const float*)d_in[7];
  const float* bk       = (const float*)d_in[8];
  const float* Wv       = (const float*)d_in[9];
  const float* bv       = (const float*)d_in[10];
  const float* W1       = (const float*)d_in[11];
  const float* b1       = (const float*)d_in[12];
  const float* W2       = (const float*)d_in[13];
  const float* b2       = (const float*)d_in[14];
  const float* ln1_g    = (const float*)d_in[15];
  const float* ln1_b    = (const float*)d_in[16];
  const float* ln2_g    = (const float*)d_in[17];
  const float* ln2_b    = (const float*)d_in[18];
  const float* lnf_g    = (const float*)d_in[19];
  const float* lnf_b    = (const float*)d_in[20];
  const float* head_w   = (const float*)d_in[21];
  const float* head_b   = (const float*)d_in[22];
  float* out = (float*)d_out;

  // per-layer transposed-weight sizes (bf16 elems)
  const long WQKV = (long)QKVN * DIM;
  const long W1SZ = (long)FF_DIM * DIM;
  const long W2SZ = (long)DIM * FF_DIM;
  const long WLAYER = WQKV + W1SZ + W2SZ;

  const long F32N = 3L * 6400 * DIM + (long)NLAYER * QKVN;
  const long BF16FIX = 6400L * DIM + 6400L * FF_DIM +
                       (long)NBATCH * DIM * KVPAD + 6400L * KVPAD +
                       (long)DIM * DIM;
  const size_t need12 = (size_t)F32N * 4 + (size_t)(BF16FIX + 12 * WLAYER) * 2;
  const bool hoist = ws_size >= need12;
  const int NW = hoist ? NLAYER : 1;

  // ---- workspace layout ----
  float* fb = (float*)d_ws;
  long fo = 0;
  float* tok      = fb + fo; fo += 6400L * DIM;
  float* b4       = fb + fo; fo += 6400L * DIM;
  float* b4b      = fb + fo; fo += 6400L * DIM;      // FF2 split-K partial 1
  float* bias_all = fb + fo; fo += (long)NLAYER * QKVN;
  __hip_bfloat16* hbuf = (__hip_bfloat16*)(fb + fo);
  long ho = 0;
  __hip_bfloat16* tok_bf = hbuf + ho; ho += 6400L * DIM;
  __hip_bfloat16* qkv    = hbuf + ho;                // alias with ffout head
  __hip_bfloat16* ffout  = hbuf + ho; ho += 6400L * FF_DIM;
  // scores f32 aliases the ffout TAIL (beyond qkv's 6400*2304 bf16 elems)
  float* scbuf = (float*)(qkv + 6400L * QKVN);
  __hip_bfloat16* vt     = hbuf + ho; ho += (long)NBATCH * DIM * KVPAD;
  __hip_bfloat16* Pb     = hbuf + ho; ho += 6400L * KVPAD;
  __hip_bfloat16* pw_t   = hbuf + ho; ho += (long)DIM * DIM;
  __hip_bfloat16* wqkv_t = hbuf + ho; ho += (long)NW * WQKV;
  __hip_bfloat16* w1_t   = hbuf + ho; ho += (long)NW * W1SZ;
  __hip_bfloat16* w2_t   = hbuf + ho; ho += (long)NW * W2SZ;

  const long DD = (long)DIM * DIM;
  const long QKVSTRIDE = (long)NTOK * QKVN;
  const long TOKSTRIDE = (long)NTOK * DIM;
  const long SCSTRIDE  = (long)NTOK * NTOK;
  const long VTSTRIDE  = (long)DIM * KVPAD;
  const long PSTRIDE   = (long)NTOK * KVPAD;

  build_qkv_bias<<<NLAYER, 256, 0, stream>>>(bq, bk, bv, bias_all);

  // hoisted all-layer weight transpose (one dispatch) if ws permits
  if (hoist) {
    wtrans_kernel<<<dim3(1584, NLAYER), 256, 0, stream>>>(
        Wq, Wk, Wv, W1, W2, wqkv_t, w1_t, w2_t, WQKV, W1SZ, W2SZ);
  }

  // ---- patch embedding ----
  im2col_kernel<<<PROWS, 256, 0, stream>>>(x, ffout);
  transpose_bf16_kernel<<<dim3(DIM / 32, DIM / 32), 256, 0, stream>>>(
      patch_w, pw_t, DIM, DIM);
  mm_nt<0, false><<<dim3(49 * 6, 1), 256, 0, stream>>>(
      ffout, 0, DIM, pw_t, 0, DIM, b4, 0, DIM, PROWS, DIM, DIM, patch_b);
  assemble_kernel<<<ROWS, 256, 0, stream>>>(b4, cls_tok, pos_emb, tok, tok_bf);

  for (int l = 0; l < NLAYER; l++) {
    __hip_bfloat16* wqkv_l = wqkv_t + (hoist ? (long)l * WQKV : 0);
    __hip_bfloat16* w1_l   = w1_t   + (hoist ? (long)l * W1SZ : 0);
    __hip_bfloat16* w2_l   = w2_t   + (hoist ? (long)l * W2SZ : 0);
    if (!hoist) {
      wtrans_kernel<<<dim3(1584, 1), 256, 0, stream>>>(
          Wq + l * DD, Wk + l * DD, Wv + l * DD,
          W1 + (long)l * DIM * FF_DIM, W2 + (long)l * FF_DIM * DIM,
          wqkv_l, w1_l, w2_l, 0, 0, 0);
    }

    // fused QKV: [6304][2304] = tok_bf @ wqkv^T + bias
    mm_nt<1, false><<<dim3(50 * (QKVN / 128), 1), 256, 0, stream>>>(
        tok_bf, 0, DIM, wqkv_l, 0, DIM, qkv, 0, QKVN,
        ROWS, QKVN, DIM, bias_all + l * QKVN);

    // V slice -> vt[b][d][tok] (zero-padded tok 197..255)
    vtrans_kernel<<<dim3(KVPAD / 64, DIM / 64, NBATCH), 256, 0, stream>>>(qkv, vt);

    // scores = Q @ K^T (f32 -> scbuf), Q/K are lda=2304 slices of qkv
    mm_nt<0, false><<<dim3(2 * 2, NBATCH), 256, 0, stream>>>(
        qkv, QKVSTRIDE, QKVN, qkv + DIM, QKVSTRIDE, QKVN, scbuf, SCSTRIDE, NTOK,
        NTOK, NTOK, DIM, nullptr);

    // gumbel + softmax (6304 blocks -> full TLP for the VALU-heavy phase)
    softmax_kernel<<<ROWS, 256, 0, stream>>>(scbuf, Pb, l);

    // attn = P @ V   (NT with B = vt, K = KVPAD=256 zero-padded)
    mm_nt<0, false><<<dim3(2 * (DIM / 128), NBATCH), 256, 0, stream>>>(
        Pb, PSTRIDE, KVPAD, vt, VTSTRIDE, KVPAD, b4, TOKSTRIDE, DIM,
        NTOK, DIM, KVPAD, nullptr);

    add_ln_kernel<<<ROWS, 256, 0, stream>>>(tok, tok_bf, b4, nullptr, nullptr,
        ln1_g + l * DIM, ln1_b + l * DIM);

    // FF1 (+bias+GELU, bf16 out); ffout overwrites qkv + scbuf (both dead)
    mm_nt<1, true><<<dim3(50 * (FF_DIM / 128), 1), 256, 0, stream>>>(
        tok_bf, 0, DIM, w1_l, 0, DIM, ffout, 0, FF_DIM,
        ROWS, FF_DIM, DIM, b1 + l * FF_DIM);

    // FF2 split-K=2 via batch-stride trick: y = k-half; partials b4, b4b.
    mm_nt<0, false><<<dim3(50 * (DIM / 128), 2), 256, 0, stream>>>(
        ffout, 1536, FF_DIM, w2_l, 1536, FF_DIM,
        b4, 6400L * DIM, DIM, ROWS, DIM, 1536, nullptr);

    // LN2 folds partial sum + b2 bias
    add_ln_kernel<<<ROWS, 256, 0, stream>>>(tok, tok_bf, b4, b4b, b2 + l * DIM,
        ln2_g + l * DIM, ln2_b + l * DIM);
  }

  head_kernel<<<NBATCH, 256, 0, stream>>>(tok, lnf_g, lnf_b, head_w, head_b, out);
}